// Round 1
// 3891.939 us; speedup vs baseline: 1.2603x; 1.2603x over previous
//
#include <hip/hip_runtime.h>

using u16 = unsigned short;
using u32 = unsigned int;
using u64 = unsigned long long;
using bf16x8 = __attribute__((ext_vector_type(8))) short;
using f32x4  = __attribute__((ext_vector_type(4))) float;
using u32x4  = __attribute__((ext_vector_type(4))) unsigned int;

// ---------------- workspace layout (bytes) ----------------
static constexpr size_t XU_OFF = 0;
static constexpr size_t XU_BYTES = (size_t)512 * 64 * 4096 * 2;      // 256 MiB
static constexpr size_t XB_OFF = XU_OFF + XU_BYTES;
static constexpr size_t XB_BYTES = (size_t)64 * 512 * 1024 * 2;      // 64 MiB
static constexpr size_t UT_OFF = XB_OFF + XB_BYTES;
static constexpr size_t WT_BYTES = (size_t)4096 * 1024 * 2;          // 8 MiB
static constexpr size_t VT_OFF = UT_OFF + WT_BYTES;
static constexpr size_t BP_OFF = VT_OFF + WT_BYTES;
static constexpr size_t BP_BYTES = 4096 * 4;
// untagged h planes: [2 parity][4 group][16 row][1024 col] u16, hi + lo
static constexpr size_t HT_PLANE = (size_t)2 * 4 * 16 * 1024 * 2;    // 256 KiB
static constexpr size_t HHI_OFF = BP_OFF + BP_BYTES;
static constexpr size_t HLO_OFF = HHI_OFF + HT_PLANE;
static constexpr size_t FLAG_OFF = HLO_OFF + HT_PLANE;
static constexpr size_t FLAG_BYTES = 4096;                           // flags[g*64+cb]

__device__ __forceinline__ float bf2f(u32 u) {
    return __uint_as_float(u << 16);
}
__device__ __forceinline__ u16 f2bf(float f) {
    u32 u = __float_as_uint(f);
    u32 r = (u + 0x7FFFu + ((u >> 16) & 1u)) >> 16;
    return (u16)r;
}

// fast gates: v_exp + v_rcp (err ~1e-7, far below bf16 pipeline noise)
__device__ __forceinline__ float fast_sigmoid(float x) {
    return __builtin_amdgcn_rcpf(1.f + __expf(-x));
}
__device__ __forceinline__ float fast_tanh(float x) {
    // 1 - 2/(1+e^{2x}); exact at +/-inf saturation, NaN-free
    return 1.f - 2.f * __builtin_amdgcn_rcpf(1.f + __expf(2.f * x));
}

// 16B cache-bypassing load (same coherence bits as relaxed agent atomics,
// but full-64B-line MALL requests: 16 rows x 64B per wave instruction)
__device__ __forceinline__ u32x4 load16_uc(const u16* p) {
    u32x4 v;
    asm volatile("global_load_dwordx4 %0, %1, off sc0 sc1"
                 : "=v"(v)
                 : "v"(p));
    return v;
}

// counted wait for load pair j (16 loads issued, order hi0,lo0,...,hi7,lo7).
// The "+v" ties make the consuming MFMAs data-depend on the waitcnt so the
// scheduler cannot hoist them above it (rule: MFMA hoists past bare asm).
__device__ __forceinline__ void wait_vm_pair(int j, u32x4& a, u32x4& b) {
    switch (j) {
    case 0: asm volatile("s_waitcnt vmcnt(14)" : "+v"(a), "+v"(b)); break;
    case 1: asm volatile("s_waitcnt vmcnt(12)" : "+v"(a), "+v"(b)); break;
    case 2: asm volatile("s_waitcnt vmcnt(10)" : "+v"(a), "+v"(b)); break;
    case 3: asm volatile("s_waitcnt vmcnt(8)"  : "+v"(a), "+v"(b)); break;
    case 4: asm volatile("s_waitcnt vmcnt(6)"  : "+v"(a), "+v"(b)); break;
    case 5: asm volatile("s_waitcnt vmcnt(4)"  : "+v"(a), "+v"(b)); break;
    case 6: asm volatile("s_waitcnt vmcnt(2)"  : "+v"(a), "+v"(b)); break;
    default: asm volatile("s_waitcnt vmcnt(0)" : "+v"(a), "+v"(b)); break;
    }
}

// ------------- x fp32 -> bf16 -------------
__global__ void cvt_x_kernel(const float4* __restrict__ x, uint2* __restrict__ xb) {
    int i = blockIdx.x * 256 + threadIdx.x;
#pragma unroll
    for (int k = 0; k < 8; ++k) {
        int idx = i + k * 1048576;
        float4 v = x[idx];
        uint2 o;
        o.x = (u32)f2bf(v.x) | ((u32)f2bf(v.y) << 16);
        o.y = (u32)f2bf(v.z) | ((u32)f2bf(v.w) << 16);
        xb[idx] = o;
    }
}

// ------------- repack: U/V fp32 -> bf16, K-contiguous, gate-interleaved columns -------------
__global__ void repack_kernel(const float* U0, const float* U1, const float* U2, const float* U3,
                              const float* V0, const float* V1, const float* V2, const float* V3,
                              u16* UT, u16* VT) {
    __shared__ u16 tile[64][65];
    int bx  = blockIdx.x;
    int mat = bx >> 8;
    int rem = bx & 255;
    int tf = rem >> 4, th = rem & 15;
    int f0 = tf * 64, h0 = th * 64;
    const float* srcs[8] = {U0, U1, U2, U3, V0, V1, V2, V3};
    const float* s = srcs[mat];
    u16* d = (mat < 4) ? UT : VT;
    int g = mat & 3;
    int c = threadIdx.x & 63;
    int r = threadIdx.x >> 6;
#pragma unroll
    for (int i = 0; i < 16; ++i) {
        int fr = r + i * 4;
        tile[fr][c] = f2bf(s[(size_t)(f0 + fr) * 1024 + h0 + c]);
    }
    __syncthreads();
#pragma unroll
    for (int i = 0; i < 16; ++i) {
        int hcl = r + i * 4;
        d[(size_t)((h0 + hcl) * 4 + g) * 1024 + f0 + c] = tile[c][hcl];
    }
}

// ------------- bias pack -------------
__global__ void bias_kernel(const float* b0, const float* b1, const float* b2, const float* b3,
                            float* bp) {
    int n = blockIdx.x * 256 + threadIdx.x;
    int g = n & 3, hc = n >> 2;
    const float* bs[4] = {b0, b1, b2, b3};
    bp[n] = bs[g][hc];
}

// ------------- xU GEMM -------------
__global__ void __launch_bounds__(256) gemm_xu_kernel(const u16* __restrict__ xb,
                                                      const u16* __restrict__ UT,
                                                      const float* __restrict__ bp,
                                                      u16* __restrict__ xu) {
    int bx = blockIdx.x;
    int nt = bx & 31, mt = bx >> 5;
    int tid = threadIdx.x;
    int lane = tid & 63, wv = tid >> 6;
    int wm = wv & 1, wn = wv >> 1;
    int l15 = lane & 15, quad = lane >> 4;

    int arow0 = mt * 128 + wm * 64 + l15;
    int brow0 = nt * 128 + wn * 64 + l15;

    f32x4 acc[4][4];
#pragma unroll
    for (int i = 0; i < 4; ++i)
#pragma unroll
        for (int j = 0; j < 4; ++j) acc[i][j] = f32x4{0.f, 0.f, 0.f, 0.f};

    float biasv[4];
#pragma unroll
    for (int j = 0; j < 4; ++j) biasv[j] = bp[brow0 + 16 * j];

    const u16* abase = xb + (size_t)arow0 * 1024;
    const u16* bbase = UT + (size_t)brow0 * 1024;

#pragma unroll 2
    for (int kk = 0; kk < 32; ++kk) {
        int ko = kk * 32 + quad * 8;
        bf16x8 af[4], bfv[4];
#pragma unroll
        for (int i = 0; i < 4; ++i)
            af[i] = *(const bf16x8*)(abase + (size_t)i * 16 * 1024 + ko);
#pragma unroll
        for (int j = 0; j < 4; ++j)
            bfv[j] = *(const bf16x8*)(bbase + (size_t)j * 16 * 1024 + ko);
#pragma unroll
        for (int i = 0; i < 4; ++i)
#pragma unroll
            for (int j = 0; j < 4; ++j)
                acc[i][j] = __builtin_amdgcn_mfma_f32_16x16x32_bf16(af[i], bfv[j], acc[i][j], 0, 0, 0);
    }

#pragma unroll
    for (int i = 0; i < 4; ++i) {
        int rbase = mt * 128 + wm * 64 + 16 * i + quad * 4;
#pragma unroll
        for (int j = 0; j < 4; ++j) {
            int col = brow0 + 16 * j;
            float bj = biasv[j];
#pragma unroll
            for (int rg = 0; rg < 4; ++rg) {
                int r = rbase + rg;
                int b_i = r >> 9, t_i = r & 511;
                xu[((size_t)(t_i * 64 + b_i) << 12) + col] = f2bf(acc[i][j][rg] + bj);
            }
        }
    }
}

// ------------- recurrent scan: flags + uncached 16B h loads, split-K, no inv -------------
// 256 blocks x 256 threads, 1/CU. Group g=bx&3 owns batch rows [16g,16g+16);
// block cb=bx>>2 owns packed cols [64cb,64cb+64). V-slice in LDS.
// Per step: wave wv polls flags of its 16 producers [16wv,16wv+16), then
// streams untagged h hi/lo via cache-bypassing global_load_dwordx4 (sc0 sc1)
// -- full 64B MALL lines, half the request count of the old u64 pairs.
// Counted vmcnt(14-2j) waits let MFMA pair j start while later lines stream.
// Split-K partials reduced via LDS zs[4][64][17]. Publish: write-through u16
// stores + vmcnt drain (stores ONLY -- xu prefetch moved after the flag store
// so its HBM miss hides under the next poll window instead of the drain).
// Parity-slot safety: block publishes h_{t+2} (overwriting h_t) only after
// all 4 waves saw flags>=t+1 from all 64 blocks (union of wave subsets).
__global__ void __launch_bounds__(256) lstm_rec_kernel(const u16* __restrict__ xu,
                                                       const u16* __restrict__ VT,
                                                       u16* hhi,
                                                       u16* hlo,
                                                       u32* flags,
                                                       float* __restrict__ out) {
    constexpr int VS_STRIDE = 1032;
    __shared__ u16  Vs[64 * VS_STRIDE];          // 132,096 B
    __shared__ float zs[4][64][17];              // 17,408 B

    int bx = blockIdx.x;
    int g  = bx & 3;
    int cb = bx >> 2;
    int tid = threadIdx.x;
    int lane = tid & 63, wv = tid >> 6;
    int l15 = lane & 15, quad = lane >> 4;
    int r  = tid >> 4;                            // batch row within group
    int hc = tid & 15;                            // h-col within block
    int wv8 = wv * 8;

    {   // stage V-slice: packed cols [64cb, 64cb+64), K-contiguous
        const u16* src = VT + (size_t)cb * 64 * 1024;
#pragma unroll
        for (int it = 0; it < 32; ++it) {
            int id = it * 256 + tid;
            int row = id >> 7;
            int c8  = id & 127;
            *(uint4*)&Vs[row * VS_STRIDE + c8 * 8] = *(const uint4*)(src + row * 1024 + c8 * 8);
        }
    }
    __syncthreads();

    u32* gflags = flags + g * 64;
    int myp = 16 * wv + l15;                      // producer polled by this lane

    float c = 0.f;
    float h = 0.f;

    uint2 xraw = *(const uint2*)(xu + ((size_t)(g * 16 + r) << 12) + cb * 64 + hc * 4);

    for (int t = 0; t < 512; ++t) {
        f32x4 acc[4];
#pragma unroll
        for (int nt = 0; nt < 4; ++nt) acc[nt] = f32x4{0.f, 0.f, 0.f, 0.f};

        if (t) {
            // 1) poll this wave's 16 producers (lanes replicate x4; ballot all-set)
            for (;;) {
                u32 f = __hip_atomic_load(gflags + myp, __ATOMIC_RELAXED,
                                          __HIP_MEMORY_SCOPE_AGENT);
                if (__ballot(f >= (u32)t) == ~0ull) break;
                __builtin_amdgcn_s_sleep(1);
            }
            asm volatile("" ::: "memory");        // keep h loads below the poll

            // 2) stream h fragments: 16B uncached loads, full-line MALL reads
            const u16* hiB = hhi + (((size_t)(t & 1) * 4 + g) * 16 + l15) * 1024;
            const u16* loB = hlo + (((size_t)(t & 1) * 4 + g) * 16 + l15) * 1024;
            u32x4 hv[8], lv[8];
#pragma unroll
            for (int j = 0; j < 8; ++j) {
                hv[j] = load16_uc(hiB + (wv8 + j) * 32 + quad * 8);
                lv[j] = load16_uc(loB + (wv8 + j) * 32 + quad * 8);
            }
#pragma unroll
            for (int j = 0; j < 8; ++j) {
                wait_vm_pair(j, hv[j], lv[j]);    // vmcnt(14-2j), ties block MFMA hoist
                union { u32x4 q; bf16x8 v; } ah, al;
                ah.q = hv[j];
                al.q = lv[j];
#pragma unroll
                for (int nt = 0; nt < 4; ++nt) {
                    bf16x8 bfr = *(const bf16x8*)(Vs + (nt * 16 + l15) * VS_STRIDE +
                                                  (wv8 + j) * 32 + quad * 8);
                    acc[nt] = __builtin_amdgcn_mfma_f32_16x16x32_bf16(ah.v, bfr, acc[nt], 0, 0, 0);
                    acc[nt] = __builtin_amdgcn_mfma_f32_16x16x32_bf16(al.v, bfr, acc[nt], 0, 0, 0);
                }
            }
        }

        // 3) split-K partial handoff: C layout col=l15, row=quad*4+rg
#pragma unroll
        for (int nt = 0; nt < 4; ++nt)
#pragma unroll
            for (int rg = 0; rg < 4; ++rg)
                zs[wv][nt * 16 + l15][quad * 4 + rg] = acc[nt][rg];
        __syncthreads();

        float z0 = zs[0][hc*4+0][r] + zs[1][hc*4+0][r] + zs[2][hc*4+0][r] + zs[3][hc*4+0][r]
                 + bf2f(xraw.x & 0xFFFFu);
        float z1 = zs[0][hc*4+1][r] + zs[1][hc*4+1][r] + zs[2][hc*4+1][r] + zs[3][hc*4+1][r]
                 + bf2f(xraw.x >> 16);
        float z2 = zs[0][hc*4+2][r] + zs[1][hc*4+2][r] + zs[2][hc*4+2][r] + zs[3][hc*4+2][r]
                 + bf2f(xraw.y & 0xFFFFu);
        float z3 = zs[0][hc*4+3][r] + zs[1][hc*4+3][r] + zs[2][hc*4+3][r] + zs[3][hc*4+3][r]
                 + bf2f(xraw.y >> 16);

        float it_ = fast_sigmoid(z0);
        float ft_ = fast_sigmoid(z1);
        float gt_ = fast_tanh(z2);
        float ot_ = fast_tanh(z3);   // reference uses tanh for output gate
        c = ft_ * c + it_ * gt_;
        h = ot_ * fast_tanh(c);

        if (t == 511) break;     // final h never read back

        // 4) publish h (write-through) + drain (stores only) + block flag
        u32 hh = f2bf(h);
        float hl = h - bf2f(hh);
        size_t sidx = (((size_t)((t + 1) & 1) * 4 + g) * 16 + r) * 1024 + cb * 16 + hc;
        __hip_atomic_store(hhi + sidx, (u16)hh, __ATOMIC_RELAXED,
                           __HIP_MEMORY_SCOPE_AGENT);
        __hip_atomic_store(hlo + sidx, f2bf(hl), __ATOMIC_RELAXED,
                           __HIP_MEMORY_SCOPE_AGENT);
        asm volatile("s_waitcnt vmcnt(0)" ::: "memory");
        __syncthreads();          // also protects zs reuse next iteration
        if (tid == 0)
            __hip_atomic_store(gflags + cb, (u32)(t + 1), __ATOMIC_RELAXED,
                               __HIP_MEMORY_SCOPE_AGENT);

        // 5) prefetch next xu AFTER the flag: its HBM-miss latency hides under
        //    the next poll window instead of sitting in the publish drain.
        xraw = *(const uint2*)(xu + ((size_t)((t + 1) * 64 + g * 16 + r) << 12) + cb * 64 + hc * 4);
    }

    out[(size_t)(g * 16 + r) * 1024 + cb * 16 + hc] = h;
}

extern "C" void kernel_launch(void* const* d_in, const int* in_sizes, int n_in,
                              void* d_out, int out_size, void* d_ws, size_t ws_size,
                              hipStream_t stream) {
    char* ws = (char*)d_ws;
    const float* x = (const float*)d_in[0];
    const float *U[4], *V[4], *b[4];
    for (int g = 0; g < 4; ++g) {
        U[g] = (const float*)d_in[1 + 3 * g];
        V[g] = (const float*)d_in[2 + 3 * g];
        b[g] = (const float*)d_in[3 + 3 * g];
    }
    u16*   xu = (u16*)(ws + XU_OFF);
    u16*   xb = (u16*)(ws + XB_OFF);
    u16*   UT = (u16*)(ws + UT_OFF);
    u16*   VT = (u16*)(ws + VT_OFF);
    float* bp = (float*)(ws + BP_OFF);
    u16*   hhi = (u16*)(ws + HHI_OFF);
    u16*   hlo = (u16*)(ws + HLO_OFF);
    u32*   flags = (u32*)(ws + FLAG_OFF);
    float* out = (float*)d_out;

    // flags must start at 0 (0xAA poison would satisfy any poll immediately)
    hipMemsetAsync(ws + FLAG_OFF, 0, FLAG_BYTES, stream);

    cvt_x_kernel<<<4096, 256, 0, stream>>>((const float4*)x, (uint2*)xb);
    repack_kernel<<<2048, 256, 0, stream>>>(U[0], U[1], U[2], U[3],
                                            V[0], V[1], V[2], V[3], UT, VT);
    bias_kernel<<<16, 256, 0, stream>>>(b[0], b[1], b[2], b[3], bp);
    gemm_xu_kernel<<<8192, 256, 0, stream>>>(xb, UT, bp, xu);

    void* args[] = {(void*)&xu, (void*)&VT, (void*)&hhi, (void*)&hlo,
                    (void*)&flags, (void*)&out};
    hipLaunchCooperativeKernel((const void*)lstm_rec_kernel, dim3(256), dim3(256),
                               args, 0, stream);
}

// Round 2
// 3453.859 us; speedup vs baseline: 1.4202x; 1.1268x over previous
//
#include <hip/hip_runtime.h>

using u16 = unsigned short;
using u32 = unsigned int;
using u64 = unsigned long long;
using bf16x8 = __attribute__((ext_vector_type(8))) short;
using f32x4  = __attribute__((ext_vector_type(4))) float;
using u32x4  = __attribute__((ext_vector_type(4))) unsigned int;

// ---------------- workspace layout (bytes) ----------------
static constexpr size_t XU_OFF = 0;
static constexpr size_t XU_BYTES = (size_t)512 * 64 * 4096 * 2;      // 256 MiB
static constexpr size_t XB_OFF = XU_OFF + XU_BYTES;
static constexpr size_t XB_BYTES = (size_t)64 * 512 * 1024 * 2;      // 64 MiB
static constexpr size_t UT_OFF = XB_OFF + XB_BYTES;
static constexpr size_t WT_BYTES = (size_t)4096 * 1024 * 2;          // 8 MiB
static constexpr size_t VT_OFF = UT_OFF + WT_BYTES;
static constexpr size_t BP_OFF = VT_OFF + WT_BYTES;
static constexpr size_t BP_BYTES = 4096 * 4;
// untagged h planes: [2 parity][4 group][16 row][1024 col] u16, hi + lo
static constexpr size_t HT_PLANE = (size_t)2 * 4 * 16 * 1024 * 2;    // 256 KiB
static constexpr size_t HHI_OFF = BP_OFF + BP_BYTES;
static constexpr size_t HLO_OFF = HHI_OFF + HT_PLANE;
static constexpr size_t FLAG_OFF = HLO_OFF + HT_PLANE;
static constexpr size_t FLAG_BYTES = 4096;                           // flags[g*64+cb], cb<32 used

__device__ __forceinline__ float bf2f(u32 u) {
    return __uint_as_float(u << 16);
}
__device__ __forceinline__ u16 f2bf(float f) {
    u32 u = __float_as_uint(f);
    u32 r = (u + 0x7FFFu + ((u >> 16) & 1u)) >> 16;
    return (u16)r;
}

// fast gates: v_exp + v_rcp (err ~1e-7, far below bf16 pipeline noise)
__device__ __forceinline__ float fast_sigmoid(float x) {
    return __builtin_amdgcn_rcpf(1.f + __expf(-x));
}
__device__ __forceinline__ float fast_tanh(float x) {
    return 1.f - 2.f * __builtin_amdgcn_rcpf(1.f + __expf(2.f * x));
}

// 16B cache-bypassing load (full-64B-line MALL requests)
__device__ __forceinline__ u32x4 load16_uc(const u16* p) {
    u32x4 v;
    asm volatile("global_load_dwordx4 %0, %1, off sc0 sc1"
                 : "=v"(v)
                 : "v"(p));
    return v;
}

// counted wait for load pair j (8 loads issued: hi0,lo0,...,hi3,lo3).
// NOTE: the xu prefetch may still be outstanding and was issued BEFORE these
// 8 loads, so vmcnt(6-2j) is still safe (oldest-first completion).
__device__ __forceinline__ void wait_vm_pair4(int j, u32x4& a, u32x4& b) {
    switch (j) {
    case 0:  asm volatile("s_waitcnt vmcnt(6)" : "+v"(a), "+v"(b)); break;
    case 1:  asm volatile("s_waitcnt vmcnt(4)" : "+v"(a), "+v"(b)); break;
    case 2:  asm volatile("s_waitcnt vmcnt(2)" : "+v"(a), "+v"(b)); break;
    default: asm volatile("s_waitcnt vmcnt(0)" : "+v"(a), "+v"(b)); break;
    }
}

// ------------- x fp32 -> bf16 -------------
__global__ void cvt_x_kernel(const float4* __restrict__ x, uint2* __restrict__ xb) {
    int i = blockIdx.x * 256 + threadIdx.x;
#pragma unroll
    for (int k = 0; k < 8; ++k) {
        int idx = i + k * 1048576;
        float4 v = x[idx];
        uint2 o;
        o.x = (u32)f2bf(v.x) | ((u32)f2bf(v.y) << 16);
        o.y = (u32)f2bf(v.z) | ((u32)f2bf(v.w) << 16);
        xb[idx] = o;
    }
}

// ------------- repack: U/V fp32 -> bf16, K-contiguous, gate-interleaved columns -------------
__global__ void repack_kernel(const float* U0, const float* U1, const float* U2, const float* U3,
                              const float* V0, const float* V1, const float* V2, const float* V3,
                              u16* UT, u16* VT) {
    __shared__ u16 tile[64][65];
    int bx  = blockIdx.x;
    int mat = bx >> 8;
    int rem = bx & 255;
    int tf = rem >> 4, th = rem & 15;
    int f0 = tf * 64, h0 = th * 64;
    const float* srcs[8] = {U0, U1, U2, U3, V0, V1, V2, V3};
    const float* s = srcs[mat];
    u16* d = (mat < 4) ? UT : VT;
    int g = mat & 3;
    int c = threadIdx.x & 63;
    int r = threadIdx.x >> 6;
#pragma unroll
    for (int i = 0; i < 16; ++i) {
        int fr = r + i * 4;
        tile[fr][c] = f2bf(s[(size_t)(f0 + fr) * 1024 + h0 + c]);
    }
    __syncthreads();
#pragma unroll
    for (int i = 0; i < 16; ++i) {
        int hcl = r + i * 4;
        d[(size_t)((h0 + hcl) * 4 + g) * 1024 + f0 + c] = tile[c][hcl];
    }
}

// ------------- bias pack -------------
__global__ void bias_kernel(const float* b0, const float* b1, const float* b2, const float* b3,
                            float* bp) {
    int n = blockIdx.x * 256 + threadIdx.x;
    int g = n & 3, hc = n >> 2;
    const float* bs[4] = {b0, b1, b2, b3};
    bp[n] = bs[g][hc];
}

// ------------- xU GEMM -------------
__global__ void __launch_bounds__(256) gemm_xu_kernel(const u16* __restrict__ xb,
                                                      const u16* __restrict__ UT,
                                                      const float* __restrict__ bp,
                                                      u16* __restrict__ xu) {
    int bx = blockIdx.x;
    int nt = bx & 31, mt = bx >> 5;
    int tid = threadIdx.x;
    int lane = tid & 63, wv = tid >> 6;
    int wm = wv & 1, wn = wv >> 1;
    int l15 = lane & 15, quad = lane >> 4;

    int arow0 = mt * 128 + wm * 64 + l15;
    int brow0 = nt * 128 + wn * 64 + l15;

    f32x4 acc[4][4];
#pragma unroll
    for (int i = 0; i < 4; ++i)
#pragma unroll
        for (int j = 0; j < 4; ++j) acc[i][j] = f32x4{0.f, 0.f, 0.f, 0.f};

    float biasv[4];
#pragma unroll
    for (int j = 0; j < 4; ++j) biasv[j] = bp[brow0 + 16 * j];

    const u16* abase = xb + (size_t)arow0 * 1024;
    const u16* bbase = UT + (size_t)brow0 * 1024;

#pragma unroll 2
    for (int kk = 0; kk < 32; ++kk) {
        int ko = kk * 32 + quad * 8;
        bf16x8 af[4], bfv[4];
#pragma unroll
        for (int i = 0; i < 4; ++i)
            af[i] = *(const bf16x8*)(abase + (size_t)i * 16 * 1024 + ko);
#pragma unroll
        for (int j = 0; j < 4; ++j)
            bfv[j] = *(const bf16x8*)(bbase + (size_t)j * 16 * 1024 + ko);
#pragma unroll
        for (int i = 0; i < 4; ++i)
#pragma unroll
            for (int j = 0; j < 4; ++j)
                acc[i][j] = __builtin_amdgcn_mfma_f32_16x16x32_bf16(af[i], bfv[j], acc[i][j], 0, 0, 0);
    }

#pragma unroll
    for (int i = 0; i < 4; ++i) {
        int rbase = mt * 128 + wm * 64 + 16 * i + quad * 4;
#pragma unroll
        for (int j = 0; j < 4; ++j) {
            int col = brow0 + 16 * j;
            float bj = biasv[j];
#pragma unroll
            for (int rg = 0; rg < 4; ++rg) {
                int r = rbase + rg;
                int b_i = r >> 9, t_i = r & 511;
                xu[((size_t)(t_i * 64 + b_i) << 12) + col] = f2bf(acc[i][j][rg] + bj);
            }
        }
    }
}

// ------------- recurrent scan: V-in-registers, 128 fat blocks -------------
// 128 blocks x 512 threads (8 waves), 1/CU on 128 CUs. Group g=bx&3 owns batch
// rows [16g,16g+16); block cb=bx>>2 owns packed cols [128cb,128cb+128)
// (h-cols [32cb,32cb+32)). V-slice lives ENTIRELY IN REGISTERS: each lane's
// 32 B-fragments (8 nt x 4 j x 16B = 128 VGPRs) are fixed across all 512
// steps -- no LDS staging, no ds_read in the MFMA loop, no bank conflicts.
// Wave wv owns K-chunk [128wv,128wv+128): polls its 4 producers [4wv,4wv+4);
// the 8-wave union covers all 32 group blocks (parity-slot safety proof
// unchanged). h broadcast per step: 128 blocks x 64KB = 8MB (was 16MB).
// Split-K partials reduced via LDS zs[8][16][132] (writes 2-way = free,
// reads are float4). Publish/drain/flag/prefetch ordering as before.
__global__ void __launch_bounds__(512, 2) lstm_rec_kernel(const u16* __restrict__ xu,
                                                          const u16* __restrict__ VT,
                                                          u16* hhi,
                                                          u16* hlo,
                                                          u32* flags,
                                                          float* __restrict__ out) {
    __shared__ float zs[8][16][132];              // 67,584 B

    int bx = blockIdx.x;
    int g  = bx & 3;
    int cb = bx >> 2;                             // 0..31
    int tid = threadIdx.x;
    int lane = tid & 63, wv = tid >> 6;           // wv 0..7
    int l15 = lane & 15, quad = lane >> 4;
    int r  = tid >> 5;                            // batch row within group, 0..15
    int hc = tid & 31;                            // h-col within block, 0..31

    // ---- V fragments in registers (one-time load, 128 VGPRs) ----
    bf16x8 vfrag[8][4];
    {
        const u16* vb = VT + ((size_t)(cb * 128 + l15) * 1024) + wv * 128 + quad * 8;
#pragma unroll
        for (int nt = 0; nt < 8; ++nt)
#pragma unroll
            for (int j = 0; j < 4; ++j)
                vfrag[nt][j] = *(const bf16x8*)(vb + (size_t)nt * 16 * 1024 + j * 32);
    }

    u32* gflags = flags + g * 64;
    int myp = 4 * wv + (lane & 3);                // producer polled by this lane

    float c = 0.f;
    float h = 0.f;

    uint2 xraw = *(const uint2*)(xu + ((size_t)(g * 16 + r) << 12) + cb * 128 + hc * 4);

    for (int t = 0; t < 512; ++t) {
        f32x4 acc[8];
#pragma unroll
        for (int nt = 0; nt < 8; ++nt) acc[nt] = f32x4{0.f, 0.f, 0.f, 0.f};

        if (t) {
            // 1) poll this wave's 4 producers (lanes replicate x16; ballot all-set)
            for (;;) {
                u32 f = __hip_atomic_load(gflags + myp, __ATOMIC_RELAXED,
                                          __HIP_MEMORY_SCOPE_AGENT);
                if (__ballot(f >= (u32)t) == ~0ull) break;
                __builtin_amdgcn_s_sleep(1);
            }
            asm volatile("" ::: "memory");        // keep h loads below the poll

            // 2) stream h fragments: 8x16B uncached loads, full-line MALL reads
            const u16* hiB = hhi + (((size_t)(t & 1) * 4 + g) * 16 + l15) * 1024
                           + wv * 128 + quad * 8;
            const u16* loB = hlo + (((size_t)(t & 1) * 4 + g) * 16 + l15) * 1024
                           + wv * 128 + quad * 8;
            u32x4 hv[4], lv[4];
#pragma unroll
            for (int j = 0; j < 4; ++j) {
                hv[j] = load16_uc(hiB + j * 32);
                lv[j] = load16_uc(loB + j * 32);
            }
#pragma unroll
            for (int j = 0; j < 4; ++j) {
                wait_vm_pair4(j, hv[j], lv[j]);   // counted wait, ties block MFMA hoist
                union { u32x4 q; bf16x8 v; } ah, al;
                ah.q = hv[j];
                al.q = lv[j];
#pragma unroll
                for (int nt = 0; nt < 8; ++nt) {
                    acc[nt] = __builtin_amdgcn_mfma_f32_16x16x32_bf16(ah.v, vfrag[nt][j], acc[nt], 0, 0, 0);
                    acc[nt] = __builtin_amdgcn_mfma_f32_16x16x32_bf16(al.v, vfrag[nt][j], acc[nt], 0, 0, 0);
                }
            }
        }

        // 3) split-K partial handoff: C layout col=l15, row=quad*4+rg
        //    zs[wv][row][col]: write banks = 16*quad + l15 (+const) -> 2-way, free
#pragma unroll
        for (int nt = 0; nt < 8; ++nt)
#pragma unroll
            for (int rg = 0; rg < 4; ++rg)
                zs[wv][quad * 4 + rg][nt * 16 + l15] = acc[nt][rg];
        __syncthreads();

        float4 s = {0.f, 0.f, 0.f, 0.f};
#pragma unroll
        for (int w = 0; w < 8; ++w) {
            float4 v = *(const float4*)&zs[w][r][hc * 4];
            s.x += v.x; s.y += v.y; s.z += v.z; s.w += v.w;
        }
        float z0 = s.x + bf2f(xraw.x & 0xFFFFu);
        float z1 = s.y + bf2f(xraw.x >> 16);
        float z2 = s.z + bf2f(xraw.y & 0xFFFFu);
        float z3 = s.w + bf2f(xraw.y >> 16);

        float it_ = fast_sigmoid(z0);
        float ft_ = fast_sigmoid(z1);
        float gt_ = fast_tanh(z2);
        float ot_ = fast_tanh(z3);   // reference uses tanh for output gate
        c = ft_ * c + it_ * gt_;
        h = ot_ * fast_tanh(c);

        if (t == 511) break;     // final h never read back

        // 4) publish h (write-through) + drain (stores only) + block flag
        u32 hh = f2bf(h);
        float hl = h - bf2f(hh);
        size_t sidx = (((size_t)((t + 1) & 1) * 4 + g) * 16 + r) * 1024 + cb * 32 + hc;
        __hip_atomic_store(hhi + sidx, (u16)hh, __ATOMIC_RELAXED,
                           __HIP_MEMORY_SCOPE_AGENT);
        __hip_atomic_store(hlo + sidx, f2bf(hl), __ATOMIC_RELAXED,
                           __HIP_MEMORY_SCOPE_AGENT);
        asm volatile("s_waitcnt vmcnt(0)" ::: "memory");
        __syncthreads();          // also protects zs reuse next iteration
        if (tid == 0)
            __hip_atomic_store(gflags + cb, (u32)(t + 1), __ATOMIC_RELAXED,
                               __HIP_MEMORY_SCOPE_AGENT);

        // 5) prefetch next xu AFTER the flag: its HBM-miss latency hides under
        //    the next poll window instead of sitting in the publish drain.
        xraw = *(const uint2*)(xu + ((size_t)((t + 1) * 64 + g * 16 + r) << 12) + cb * 128 + hc * 4);
    }

    out[(size_t)(g * 16 + r) * 1024 + cb * 32 + hc] = h;
}

extern "C" void kernel_launch(void* const* d_in, const int* in_sizes, int n_in,
                              void* d_out, int out_size, void* d_ws, size_t ws_size,
                              hipStream_t stream) {
    char* ws = (char*)d_ws;
    const float* x = (const float*)d_in[0];
    const float *U[4], *V[4], *b[4];
    for (int g = 0; g < 4; ++g) {
        U[g] = (const float*)d_in[1 + 3 * g];
        V[g] = (const float*)d_in[2 + 3 * g];
        b[g] = (const float*)d_in[3 + 3 * g];
    }
    u16*   xu = (u16*)(ws + XU_OFF);
    u16*   xb = (u16*)(ws + XB_OFF);
    u16*   UT = (u16*)(ws + UT_OFF);
    u16*   VT = (u16*)(ws + VT_OFF);
    float* bp = (float*)(ws + BP_OFF);
    u16*   hhi = (u16*)(ws + HHI_OFF);
    u16*   hlo = (u16*)(ws + HLO_OFF);
    u32*   flags = (u32*)(ws + FLAG_OFF);
    float* out = (float*)d_out;

    // flags must start at 0 (0xAA poison would satisfy any poll immediately)
    hipMemsetAsync(ws + FLAG_OFF, 0, FLAG_BYTES, stream);

    cvt_x_kernel<<<4096, 256, 0, stream>>>((const float4*)x, (uint2*)xb);
    repack_kernel<<<2048, 256, 0, stream>>>(U[0], U[1], U[2], U[3],
                                            V[0], V[1], V[2], V[3], UT, VT);
    bias_kernel<<<16, 256, 0, stream>>>(b[0], b[1], b[2], b[3], bp);
    gemm_xu_kernel<<<8192, 256, 0, stream>>>(xb, UT, bp, xu);

    void* args[] = {(void*)&xu, (void*)&VT, (void*)&hhi, (void*)&hlo,
                    (void*)&flags, (void*)&out};
    hipLaunchCooperativeKernel((const void*)lstm_rec_kernel, dim3(128), dim3(512),
                               args, 0, stream);
}

// Round 3
// 2814.457 us; speedup vs baseline: 1.7428x; 1.2272x over previous
//
#include <hip/hip_runtime.h>

using u16 = unsigned short;
using u32 = unsigned int;
using u64 = unsigned long long;
using bf16x8 = __attribute__((ext_vector_type(8))) short;
using f16x8  = __attribute__((ext_vector_type(8))) _Float16;
using f32x4  = __attribute__((ext_vector_type(4))) float;
using u32x4  = __attribute__((ext_vector_type(4))) unsigned int;

// ---------------- workspace layout (bytes) ----------------
static constexpr size_t XU_OFF = 0;
static constexpr size_t XU_BYTES = (size_t)512 * 64 * 4096 * 2;      // 256 MiB
static constexpr size_t XB_OFF = XU_OFF + XU_BYTES;
static constexpr size_t XB_BYTES = (size_t)64 * 512 * 1024 * 2;      // 64 MiB
static constexpr size_t UT_OFF = XB_OFF + XB_BYTES;
static constexpr size_t WT_BYTES = (size_t)4096 * 1024 * 2;          // 8 MiB
static constexpr size_t VT_OFF = UT_OFF + WT_BYTES;
static constexpr size_t BP_OFF = VT_OFF + WT_BYTES;
static constexpr size_t BP_BYTES = 4096 * 4;
// untagged h plane: [2 parity][4 group][16 row][1024 col] u16 (fp16 now)
static constexpr size_t HT_PLANE = (size_t)2 * 4 * 16 * 1024 * 2;    // 256 KiB
static constexpr size_t HHI_OFF = BP_OFF + BP_BYTES;
static constexpr size_t HLO_OFF = HHI_OFF + HT_PLANE;                // unused (kept for layout)
static constexpr size_t FLAG_OFF = HLO_OFF + HT_PLANE;
static constexpr size_t FLAG_BYTES = 4096;                           // flags[g*64+cb], cb<32 used

__device__ __forceinline__ float bf2f(u32 u) {
    return __uint_as_float(u << 16);
}
__device__ __forceinline__ u16 f2bf(float f) {
    u32 u = __float_as_uint(f);
    u32 r = (u + 0x7FFFu + ((u >> 16) & 1u)) >> 16;
    return (u16)r;
}
__device__ __forceinline__ u16 f2h(float f) {
    _Float16 x = (_Float16)f;                     // RTN
    union { _Float16 h; u16 u; } cv;
    cv.h = x;
    return cv.u;
}

// fast gates: v_exp + v_rcp (err ~1e-7, far below bf16 pipeline noise)
__device__ __forceinline__ float fast_sigmoid(float x) {
    return __builtin_amdgcn_rcpf(1.f + __expf(-x));
}
__device__ __forceinline__ float fast_tanh(float x) {
    return 1.f - 2.f * __builtin_amdgcn_rcpf(1.f + __expf(2.f * x));
}

// 16B cache-bypassing load (full-64B-line MALL requests)
__device__ __forceinline__ u32x4 load16_uc(const u16* p) {
    u32x4 v;
    asm volatile("global_load_dwordx4 %0, %1, off sc0 sc1"
                 : "=v"(v)
                 : "v"(p));
    return v;
}

// counted wait for h load j (4 loads issued; the xu prefetch may still be
// outstanding and is OLDER than these, so vmcnt(3-j) also drains it first --
// oldest-first completion keeps this safe).
__device__ __forceinline__ void wait_vm4(int j, u32x4& a) {
    switch (j) {
    case 0:  asm volatile("s_waitcnt vmcnt(3)" : "+v"(a)); break;
    case 1:  asm volatile("s_waitcnt vmcnt(2)" : "+v"(a)); break;
    case 2:  asm volatile("s_waitcnt vmcnt(1)" : "+v"(a)); break;
    default: asm volatile("s_waitcnt vmcnt(0)" : "+v"(a)); break;
    }
}

// ------------- x fp32 -> bf16 -------------
__global__ void cvt_x_kernel(const float4* __restrict__ x, uint2* __restrict__ xb) {
    int i = blockIdx.x * 256 + threadIdx.x;
#pragma unroll
    for (int k = 0; k < 8; ++k) {
        int idx = i + k * 1048576;
        float4 v = x[idx];
        uint2 o;
        o.x = (u32)f2bf(v.x) | ((u32)f2bf(v.y) << 16);
        o.y = (u32)f2bf(v.z) | ((u32)f2bf(v.w) << 16);
        xb[idx] = o;
    }
}

// ------------- repack: U fp32->bf16, V fp32->fp16; K-contiguous, gate-interleaved columns -------------
__global__ void repack_kernel(const float* U0, const float* U1, const float* U2, const float* U3,
                              const float* V0, const float* V1, const float* V2, const float* V3,
                              u16* UT, u16* VT) {
    __shared__ u16 tile[64][65];
    int bx  = blockIdx.x;
    int mat = bx >> 8;
    int rem = bx & 255;
    int tf = rem >> 4, th = rem & 15;
    int f0 = tf * 64, h0 = th * 64;
    const float* srcs[8] = {U0, U1, U2, U3, V0, V1, V2, V3};
    const float* s = srcs[mat];
    u16* d = (mat < 4) ? UT : VT;
    bool isU = (mat < 4);
    int g = mat & 3;
    int c = threadIdx.x & 63;
    int r = threadIdx.x >> 6;
#pragma unroll
    for (int i = 0; i < 16; ++i) {
        int fr = r + i * 4;
        float v = s[(size_t)(f0 + fr) * 1024 + h0 + c];
        tile[fr][c] = isU ? f2bf(v) : f2h(v);
    }
    __syncthreads();
#pragma unroll
    for (int i = 0; i < 16; ++i) {
        int hcl = r + i * 4;
        d[(size_t)((h0 + hcl) * 4 + g) * 1024 + f0 + c] = tile[c][hcl];
    }
}

// ------------- bias pack -------------
__global__ void bias_kernel(const float* b0, const float* b1, const float* b2, const float* b3,
                            float* bp) {
    int n = blockIdx.x * 256 + threadIdx.x;
    int g = n & 3, hc = n >> 2;
    const float* bs[4] = {b0, b1, b2, b3};
    bp[n] = bs[g][hc];
}

// ------------- xU GEMM -------------
// XCD-chunked swizzle: 8192 blocks, 8 XCDs -> each XCD gets a contiguous 1024-
// block chunk. Runs of 32 consecutive blocks share an A-panel (same mt) and a
// chunk spans all 32 nt values, so A-panels and the whole 8MB UT stay L2-hot
// per XCD instead of being refetched from MALL by all 8.
__global__ void __launch_bounds__(256) gemm_xu_kernel(const u16* __restrict__ xb,
                                                      const u16* __restrict__ UT,
                                                      const float* __restrict__ bp,
                                                      u16* __restrict__ xu) {
    int bx0 = blockIdx.x;
    int bx = (bx0 & 7) * 1024 + (bx0 >> 3);       // bijective (8192 % 8 == 0)
    int nt = bx & 31, mt = bx >> 5;
    int tid = threadIdx.x;
    int lane = tid & 63, wv = tid >> 6;
    int wm = wv & 1, wn = wv >> 1;
    int l15 = lane & 15, quad = lane >> 4;

    int arow0 = mt * 128 + wm * 64 + l15;
    int brow0 = nt * 128 + wn * 64 + l15;

    f32x4 acc[4][4];
#pragma unroll
    for (int i = 0; i < 4; ++i)
#pragma unroll
        for (int j = 0; j < 4; ++j) acc[i][j] = f32x4{0.f, 0.f, 0.f, 0.f};

    float biasv[4];
#pragma unroll
    for (int j = 0; j < 4; ++j) biasv[j] = bp[brow0 + 16 * j];

    const u16* abase = xb + (size_t)arow0 * 1024;
    const u16* bbase = UT + (size_t)brow0 * 1024;

#pragma unroll 2
    for (int kk = 0; kk < 32; ++kk) {
        int ko = kk * 32 + quad * 8;
        bf16x8 af[4], bfv[4];
#pragma unroll
        for (int i = 0; i < 4; ++i)
            af[i] = *(const bf16x8*)(abase + (size_t)i * 16 * 1024 + ko);
#pragma unroll
        for (int j = 0; j < 4; ++j)
            bfv[j] = *(const bf16x8*)(bbase + (size_t)j * 16 * 1024 + ko);
#pragma unroll
        for (int i = 0; i < 4; ++i)
#pragma unroll
            for (int j = 0; j < 4; ++j)
                acc[i][j] = __builtin_amdgcn_mfma_f32_16x16x32_bf16(af[i], bfv[j], acc[i][j], 0, 0, 0);
    }

#pragma unroll
    for (int i = 0; i < 4; ++i) {
        int rbase = mt * 128 + wm * 64 + 16 * i + quad * 4;
#pragma unroll
        for (int j = 0; j < 4; ++j) {
            int col = brow0 + 16 * j;
            float bj = biasv[j];
#pragma unroll
            for (int rg = 0; rg < 4; ++rg) {
                int r = rbase + rg;
                int b_i = r >> 9, t_i = r & 511;
                xu[((size_t)(t_i * 64 + b_i) << 12) + col] = f2bf(acc[i][j][rg] + bj);
            }
        }
    }
}

// ------------- recurrent scan: fp16 single-plane h, V-in-registers -------------
// 128 blocks x 512 threads (8 waves), 1/CU. Group g=bx&3 owns batch rows
// [16g,16g+16); block cb=bx>>2 owns packed cols [128cb,128cb+128). V-slice in
// registers as fp16 (128 VGPRs/lane, fixed across steps). h is ONE fp16 plane
// (was bf16 hi+lo): fp16 V (2^-12 rel err) beats bf16 V (2^-9), so accuracy
// improves while h broadcast halves to 4MB/step, MFMA halves to 32/wave/step,
// and the publish is a single store. Wave wv owns K-chunk [128wv,128wv+128):
// polls its 4 producers [4wv,4wv+4); 8-wave union covers all 32 group blocks
// (parity-slot safety proof unchanged). Split-K partials via LDS zs[8][16][132].
__global__ void __launch_bounds__(512, 2) lstm_rec_kernel(const u16* __restrict__ xu,
                                                          const u16* __restrict__ VT,
                                                          u16* hhi,
                                                          u16* hlo,   // unused
                                                          u32* flags,
                                                          float* __restrict__ out) {
    __shared__ float zs[8][16][132];              // 67,584 B

    int bx = blockIdx.x;
    int g  = bx & 3;
    int cb = bx >> 2;                             // 0..31
    int tid = threadIdx.x;
    int lane = tid & 63, wv = tid >> 6;           // wv 0..7
    int l15 = lane & 15, quad = lane >> 4;
    int r  = tid >> 5;                            // batch row within group, 0..15
    int hc = tid & 31;                            // h-col within block, 0..31

    // ---- V fragments in registers (one-time load, 128 VGPRs, fp16) ----
    f16x8 vfrag[8][4];
    {
        const u16* vb = VT + ((size_t)(cb * 128 + l15) * 1024) + wv * 128 + quad * 8;
#pragma unroll
        for (int nt = 0; nt < 8; ++nt)
#pragma unroll
            for (int j = 0; j < 4; ++j)
                vfrag[nt][j] = *(const f16x8*)(vb + (size_t)nt * 16 * 1024 + j * 32);
    }

    u32* gflags = flags + g * 64;
    int myp = 4 * wv + (lane & 3);                // producer polled by this lane

    float c = 0.f;
    float h = 0.f;

    uint2 xraw = *(const uint2*)(xu + ((size_t)(g * 16 + r) << 12) + cb * 128 + hc * 4);

    for (int t = 0; t < 512; ++t) {
        f32x4 acc[8];
#pragma unroll
        for (int nt = 0; nt < 8; ++nt) acc[nt] = f32x4{0.f, 0.f, 0.f, 0.f};

        if (t) {
            // 1) poll this wave's 4 producers (lanes replicate x16; ballot all-set)
            for (;;) {
                u32 f = __hip_atomic_load(gflags + myp, __ATOMIC_RELAXED,
                                          __HIP_MEMORY_SCOPE_AGENT);
                if (__ballot(f >= (u32)t) == ~0ull) break;
                __builtin_amdgcn_s_sleep(1);
            }
            asm volatile("" ::: "memory");        // keep h loads below the poll

            // 2) stream h fragments: 4x16B uncached loads, full-line MALL reads
            const u16* hB = hhi + (((size_t)(t & 1) * 4 + g) * 16 + l15) * 1024
                          + wv * 128 + quad * 8;
            u32x4 hv[4];
#pragma unroll
            for (int j = 0; j < 4; ++j)
                hv[j] = load16_uc(hB + j * 32);
#pragma unroll
            for (int j = 0; j < 4; ++j) {
                wait_vm4(j, hv[j]);               // counted wait, ties block MFMA hoist
                union { u32x4 q; f16x8 v; } ah;
                ah.q = hv[j];
#pragma unroll
                for (int nt = 0; nt < 8; ++nt)
                    acc[nt] = __builtin_amdgcn_mfma_f32_16x16x32_f16(ah.v, vfrag[nt][j], acc[nt], 0, 0, 0);
            }
        }

        // 3) split-K partial handoff: C layout col=l15, row=quad*4+rg
#pragma unroll
        for (int nt = 0; nt < 8; ++nt)
#pragma unroll
            for (int rg = 0; rg < 4; ++rg)
                zs[wv][quad * 4 + rg][nt * 16 + l15] = acc[nt][rg];
        __syncthreads();

        float4 s = {0.f, 0.f, 0.f, 0.f};
#pragma unroll
        for (int w = 0; w < 8; ++w) {
            float4 v = *(const float4*)&zs[w][r][hc * 4];
            s.x += v.x; s.y += v.y; s.z += v.z; s.w += v.w;
        }
        float z0 = s.x + bf2f(xraw.x & 0xFFFFu);
        float z1 = s.y + bf2f(xraw.x >> 16);
        float z2 = s.z + bf2f(xraw.y & 0xFFFFu);
        float z3 = s.w + bf2f(xraw.y >> 16);

        float it_ = fast_sigmoid(z0);
        float ft_ = fast_sigmoid(z1);
        float gt_ = fast_tanh(z2);
        float ot_ = fast_tanh(z3);   // reference uses tanh for output gate
        c = ft_ * c + it_ * gt_;
        h = ot_ * fast_tanh(c);

        if (t == 511) break;     // final h never read back

        // 4) publish h (single fp16 write-through) + drain (stores only) + flag
        size_t sidx = (((size_t)((t + 1) & 1) * 4 + g) * 16 + r) * 1024 + cb * 32 + hc;
        __hip_atomic_store(hhi + sidx, f2h(h), __ATOMIC_RELAXED,
                           __HIP_MEMORY_SCOPE_AGENT);
        asm volatile("s_waitcnt vmcnt(0)" ::: "memory");
        __syncthreads();          // also protects zs reuse next iteration
        if (tid == 0)
            __hip_atomic_store(gflags + cb, (u32)(t + 1), __ATOMIC_RELAXED,
                               __HIP_MEMORY_SCOPE_AGENT);

        // 5) prefetch next xu AFTER the flag: its HBM-miss latency hides under
        //    the next poll window instead of sitting in the publish drain.
        xraw = *(const uint2*)(xu + ((size_t)((t + 1) * 64 + g * 16 + r) << 12) + cb * 128 + hc * 4);
    }

    out[(size_t)(g * 16 + r) * 1024 + cb * 32 + hc] = h;
}

extern "C" void kernel_launch(void* const* d_in, const int* in_sizes, int n_in,
                              void* d_out, int out_size, void* d_ws, size_t ws_size,
                              hipStream_t stream) {
    char* ws = (char*)d_ws;
    const float* x = (const float*)d_in[0];
    const float *U[4], *V[4], *b[4];
    for (int g = 0; g < 4; ++g) {
        U[g] = (const float*)d_in[1 + 3 * g];
        V[g] = (const float*)d_in[2 + 3 * g];
        b[g] = (const float*)d_in[3 + 3 * g];
    }
    u16*   xu = (u16*)(ws + XU_OFF);
    u16*   xb = (u16*)(ws + XB_OFF);
    u16*   UT = (u16*)(ws + UT_OFF);
    u16*   VT = (u16*)(ws + VT_OFF);
    float* bp = (float*)(ws + BP_OFF);
    u16*   hhi = (u16*)(ws + HHI_OFF);
    u16*   hlo = (u16*)(ws + HLO_OFF);
    u32*   flags = (u32*)(ws + FLAG_OFF);
    float* out = (float*)d_out;

    // flags must start at 0 (0xAA poison would satisfy any poll immediately)
    hipMemsetAsync(ws + FLAG_OFF, 0, FLAG_BYTES, stream);

    cvt_x_kernel<<<4096, 256, 0, stream>>>((const float4*)x, (uint2*)xb);
    repack_kernel<<<2048, 256, 0, stream>>>(U[0], U[1], U[2], U[3],
                                            V[0], V[1], V[2], V[3], UT, VT);
    bias_kernel<<<16, 256, 0, stream>>>(b[0], b[1], b[2], b[3], bp);
    gemm_xu_kernel<<<8192, 256, 0, stream>>>(xb, UT, bp, xu);

    void* args[] = {(void*)&xu, (void*)&VT, (void*)&hhi, (void*)&hlo,
                    (void*)&flags, (void*)&out};
    hipLaunchCooperativeKernel((const void*)lstm_rec_kernel, dim3(128), dim3(512),
                               args, 0, stream);
}